// Round 12
// baseline (337.266 us; speedup 1.0000x reference)
//
#include <hip/hip_runtime.h>
#include <stdint.h>

typedef __attribute__((ext_vector_type(8))) short short8;
typedef __attribute__((ext_vector_type(4))) short short4v;
typedef __attribute__((ext_vector_type(4))) float f32x4;

#define MFMA(a,b,c) __builtin_amdgcn_mfma_f32_16x16x32_bf16((a),(b),(c),0,0,0)
#define QSCALE 0.18033688f   /* 0.125 * log2(e): softmax in exp2 domain */
#define VT_LD 584
#define NTOK 577
#define PT_LD 72
#define AS1 __attribute__((address_space(1)))
#define AS3 __attribute__((address_space(3)))

__device__ __forceinline__ unsigned short f2bf(float f) {
    unsigned int u = __float_as_uint(f);
    u += 0x7fffu + ((u >> 16) & 1u);   // RNE
    return (unsigned short)(u >> 16);
}
__device__ __forceinline__ float bf2f(unsigned short u) {
    return __uint_as_float(((unsigned int)u) << 16);
}
__device__ __forceinline__ unsigned int cvt_pk_bf16(float lo, float hi) {
    unsigned int r;
    asm("v_cvt_pk_bf16_f32 %0, %1, %2" : "=v"(r) : "v"(lo), "v"(hi));
    return r;
}

// ---------------- conversions ----------------
__global__ __launch_bounds__(256) void cvt_f32_bf16(const float* __restrict__ in,
                                                    unsigned short* __restrict__ out, int n4) {
    int i = blockIdx.x * 256 + threadIdx.x;
    if (i < n4) {
        float4 v = ((const float4*)in)[i];
        short4v s;
        s[0] = (short)f2bf(v.x); s[1] = (short)f2bf(v.y);
        s[2] = (short)f2bf(v.z); s[3] = (short)f2bf(v.w);
        ((short4v*)out)[i] = s;
    }
}

// in [R][C] f32 -> out [C][R] bf16   (R,C multiples of 32)
__global__ __launch_bounds__(256) void transpose_cvt(const float* __restrict__ in,
                                                     unsigned short* __restrict__ out,
                                                     int R, int C) {
    __shared__ float tile[32][33];
    int c0 = blockIdx.x * 32, r0 = blockIdx.y * 32;
    int lc = threadIdx.x & 31, lr = threadIdx.x >> 5;
    #pragma unroll
    for (int i = 0; i < 4; ++i) {
        int r = lr + i * 8;
        tile[r][lc] = in[(size_t)(r0 + r) * C + c0 + lc];
    }
    __syncthreads();
    #pragma unroll
    for (int i = 0; i < 4; ++i) {
        int r = lr + i * 8;
        out[(size_t)(c0 + r) * R + r0 + lc] = f2bf(tile[lc][r]);
    }
}

// ---- GEMM (QKV): 128x128 tile, 4 waves, WAVE-PRIVATE panels, ZERO barriers ----
// Each wave owns A/B LDS panels (dbuf) and runs a private distance-2 counted-vmcnt
// pipeline. No s_barrier in the K-loop: waves slip freely; load-wait of one wave
// overlaps MFMA of others on the same SIMD. K=768 = 12 steps, fully unrolled.
template<int EPI>
__global__ __launch_bounds__(256, 1) void gemm_wp(
    const unsigned short* __restrict__ A,
    const unsigned short* __restrict__ Bt,
    const float* __restrict__ bias,
    unsigned short* __restrict__ q_out, unsigned short* __restrict__ k_out,
    unsigned short* __restrict__ vt_out, float* __restrict__ f_out,
    int M, int NB)
{
    __shared__ __align__(16) unsigned short AL[4][2][64 * 64];   // 64 KB
    __shared__ __align__(16) unsigned short BL[4][2][64 * 64];   // 64 KB

    const int nwg = gridDim.x, orig = blockIdx.x;
    const int qd = nwg >> 3, r8 = nwg & 7;
    const int xcd = orig & 7, j0 = orig >> 3;
    const int wg = (xcd < r8 ? xcd * (qd + 1) : r8 * (qd + 1) + (xcd - r8) * qd) + j0;
    const int bx = wg % NB, by = wg / NB;
    const int m0 = by * 128, n0 = bx * 128;

    const int t = threadIdx.x, lane = t & 63, w = t >> 6;
    const int g = lane >> 4, c = lane & 15;
    const int wr = w >> 1, wcn = w & 1;
    const int l8 = lane >> 3;                      // 0..7 (staging row-in-group)
    const int csw = (((lane & 7) ^ l8) * 8);       // pre-swizzled source chunk
    const int rch = (c & 7);                       // read-side XOR key

    f32x4 acc[4][4] = {};

    // per-wave stage of one K-tile into private panels (16 global_load_lds)
    auto stage = [&](int buf, int kt) {
        const int k0 = kt * 64;
        #pragma unroll
        for (int jj = 0; jj < 8; ++jj) {
            int arow = m0 + wr * 64 + jj * 8 + l8;
            arow = arow < M ? arow : M - 1;
            __builtin_amdgcn_global_load_lds(
                (const AS1 unsigned int*)&A[(size_t)arow * 768 + k0 + csw],
                (AS3 unsigned int*)&AL[w][buf][jj * 512], 16, 0, 0);
            int brow = n0 + wcn * 64 + jj * 8 + l8;
            __builtin_amdgcn_global_load_lds(
                (const AS1 unsigned int*)&Bt[(size_t)brow * 768 + k0 + csw],
                (AS3 unsigned int*)&BL[w][buf][jj * 512], 16, 0, 0);
        }
    };

    stage(0, 0);
    stage(1, 1);
    asm volatile("s_waitcnt vmcnt(16)" ::: "memory");   // buf0 landed
    __builtin_amdgcn_sched_barrier(0);

    #pragma unroll
    for (int kt = 0; kt < 12; ++kt) {
        const int buf = kt & 1;
        // load this tile's fragments to registers
        short8 af[2][4], bfv[2][4];
        #pragma unroll
        for (int kk = 0; kk < 2; ++kk) {
            #pragma unroll
            for (int mf = 0; mf < 4; ++mf)
                af[kk][mf] = *(const short8*)&AL[w][buf][(mf * 16 + c) * 64 + (((kk * 4 + g) ^ rch) * 8)];
            #pragma unroll
            for (int nf = 0; nf < 4; ++nf)
                bfv[kk][nf] = *(const short8*)&BL[w][buf][(nf * 16 + c) * 64 + (((kk * 4 + g) ^ rch) * 8)];
        }
        // all reads in VGPRs -> LDS slots free -> safe to overwrite same-parity buf
        asm volatile("s_waitcnt lgkmcnt(0)" ::: "memory");
        __builtin_amdgcn_sched_barrier(0);
        if (kt <= 9) stage(buf, kt + 2);
        __builtin_amdgcn_s_setprio(1);
        #pragma unroll
        for (int kk = 0; kk < 2; ++kk)
        #pragma unroll
        for (int mf = 0; mf < 4; ++mf)
        #pragma unroll
        for (int nf = 0; nf < 4; ++nf)
            acc[mf][nf] = MFMA(af[kk][mf], bfv[kk][nf], acc[mf][nf]);
        __builtin_amdgcn_s_setprio(0);
        // counted wait: next buffer's 16 loads landed, just-issued 16 stay in flight
        if (kt <= 9)       asm volatile("s_waitcnt vmcnt(16)" ::: "memory");
        else if (kt == 10) asm volatile("s_waitcnt vmcnt(0)" ::: "memory");
        __builtin_amdgcn_sched_barrier(0);
    }

    #pragma unroll
    for (int mf = 0; mf < 4; ++mf)
    #pragma unroll
    for (int nf = 0; nf < 4; ++nf) {
        int n = n0 + wcn * 64 + nf * 16 + c;
        float bv = bias[n];
        #pragma unroll
        for (int e = 0; e < 4; ++e) {
            int m = m0 + wr * 64 + mf * 16 + g * 4 + e;
            if (m >= M) continue;
            float v = acc[mf][nf][e] + bv;
            if (EPI == 0) {
                int which = n / 768;
                int rr = n - which * 768;
                int h = rr >> 6, d = rr & 63;
                int b = m / 577, tok = m - b * 577;
                int bh = b * 12 + h;
                if (which == 0)      q_out[((size_t)bh * 577 + tok) * 64 + d] = f2bf(v * QSCALE);
                else if (which == 1) k_out[((size_t)bh * 577 + tok) * 64 + d] = f2bf(v);
                else                 vt_out[((size_t)bh * 64 + d) * VT_LD + tok] = f2bf(v);
            } else {
                f_out[(size_t)m * 768 + n] = v;
            }
        }
    }
}

// ---- GEMM B (proj): R6 128x128 single-buffer 2-phase (proven) ----
template<int EPI>
__global__ __launch_bounds__(256) void gemm128(
    const unsigned short* __restrict__ A,
    const unsigned short* __restrict__ Bt,
    const float* __restrict__ bias,
    unsigned short* __restrict__ q_out, unsigned short* __restrict__ k_out,
    unsigned short* __restrict__ vt_out, float* __restrict__ f_out,
    int M, int K, int NB)
{
    __shared__ __align__(16) unsigned short As[128 * 64];
    __shared__ __align__(16) unsigned short Bs[128 * 64];

    const int nwg = gridDim.x, orig = blockIdx.x;
    const int qd = nwg >> 3, r = nwg & 7;
    const int xcd = orig & 7, j = orig >> 3;
    const int wg = (xcd < r ? xcd * (qd + 1) : r * (qd + 1) + (xcd - r) * qd) + j;
    const int bx = wg % NB, by = wg / NB;
    const int m0 = by * 128, n0 = bx * 128;

    const int t = threadIdx.x, lane = t & 63, w = t >> 6;
    const int g = lane >> 4, c = lane & 15;
    const int wr = w >> 1, wc = w & 1;
    const int rowi = t >> 3;
    const int csw = (((t & 7) ^ (rowi & 7)) * 8);

    f32x4 acc[4][4] = {};

    for (int k0 = 0; k0 < K; k0 += 64) {
        #pragma unroll
        for (int i = 0; i < 4; ++i) {
            int row = i * 32 + rowi;
            int ra = m0 + row; ra = ra < M ? ra : M - 1;
            __builtin_amdgcn_global_load_lds(
                (const AS1 unsigned int*)&A[(size_t)ra * K + k0 + csw],
                (AS3 unsigned int*)&As[(i * 256 + w * 64) * 8], 16, 0, 0);
            __builtin_amdgcn_global_load_lds(
                (const AS1 unsigned int*)&Bt[(size_t)(n0 + row) * K + k0 + csw],
                (AS3 unsigned int*)&Bs[(i * 256 + w * 64) * 8], 16, 0, 0);
        }
        __syncthreads();
        #pragma unroll
        for (int kk = 0; kk < 2; ++kk) {
            short8 af[4], bfr[4];
            #pragma unroll
            for (int mf = 0; mf < 4; ++mf) {
                int rr = wr * 64 + mf * 16 + c;
                af[mf] = *(const short8*)&As[rr * 64 + (((kk * 4 + g) ^ (c & 7)) * 8)];
            }
            #pragma unroll
            for (int nf = 0; nf < 4; ++nf) {
                int rr = wc * 64 + nf * 16 + c;
                bfr[nf] = *(const short8*)&Bs[rr * 64 + (((kk * 4 + g) ^ (c & 7)) * 8)];
            }
            __builtin_amdgcn_s_setprio(1);
            #pragma unroll
            for (int mf = 0; mf < 4; ++mf)
            #pragma unroll
            for (int nf = 0; nf < 4; ++nf)
                acc[mf][nf] = MFMA(af[mf], bfr[nf], acc[mf][nf]);
            __builtin_amdgcn_s_setprio(0);
        }
        __syncthreads();
    }

    #pragma unroll
    for (int mf = 0; mf < 4; ++mf)
    #pragma unroll
    for (int nf = 0; nf < 4; ++nf) {
        int n = n0 + wc * 64 + nf * 16 + c;
        float bv = bias[n];
        #pragma unroll
        for (int e = 0; e < 4; ++e) {
            int m = m0 + wr * 64 + mf * 16 + g * 4 + e;
            if (m >= M) continue;
            float v = acc[mf][nf][e] + bv;
            if (EPI == 0) {
                int which = n / 768;
                int rr = n - which * 768;
                int h = rr >> 6, d = rr & 63;
                int b = m / 577, tok = m - b * 577;
                int bh = b * 12 + h;
                if (which == 0)      q_out[((size_t)bh * 577 + tok) * 64 + d] = f2bf(v * QSCALE);
                else if (which == 1) k_out[((size_t)bh * 577 + tok) * 64 + d] = f2bf(v);
                else                 vt_out[((size_t)bh * 64 + d) * VT_LD + tok] = f2bf(v);
            } else {
                f_out[(size_t)m * 768 + n] = v;
            }
        }
    }
}

// ---------------- flash attention: LDS-staged K/V (2-phase dbuf), fixed-shift softmax --
__global__ __launch_bounds__(256, 3) void attn_flash(
    const unsigned short* __restrict__ Qg,
    const unsigned short* __restrict__ Kg,
    const unsigned short* __restrict__ Vtg,
    unsigned short* __restrict__ Og)
{
    __shared__ __align__(16) unsigned short KL[2][64][64];
    __shared__ __align__(16) unsigned short VL[2][64][64];
    __shared__ __align__(16) unsigned short pt[4][16][PT_LD];

    const int nwg = gridDim.x, orig = blockIdx.x;
    const int qd = nwg >> 3, jj8 = nwg & 7;
    const int xcd = orig & 7, jj = orig >> 3;
    const int wgid = (xcd < jj8 ? xcd * (qd + 1) : jj8 * (qd + 1) + (xcd - jj8) * qd) + jj;
    const int qt = wgid % 10;
    const int bh = wgid / 10;
    const int b = bh / 12, h = bh - b * 12;
    const int t = threadIdx.x, w = t >> 6, lane = t & 63;
    const int g = lane >> 4, c = lane & 15;
    const int rowi = t >> 3;                        // 0..31
    const int gch = ((t & 7) ^ (rowi & 7)) * 8;     // pre-swizzled source chunk

    const unsigned short* Qh = Qg + (size_t)bh * NTOK * 64;
    const unsigned short* Kh = Kg + (size_t)bh * NTOK * 64;
    const unsigned short* Vh = Vtg + (size_t)bh * 64 * VT_LD;

    const int q = qt * 64 + w * 16 + c;
    const int qc = q < NTOK ? q : NTOK - 1;

    short8 bq0 = *(const short8*)&Qh[(size_t)qc * 64 +      g * 8];
    short8 bq1 = *(const short8*)&Qh[(size_t)qc * 64 + 32 + g * 8];

    auto stage = [&](int buf, int kbase) {
        #pragma unroll
        for (int i = 0; i < 2; ++i) {
            __builtin_amdgcn_global_load_lds(
                (const AS1 unsigned int*)&Kh[(size_t)(kbase + i * 32 + rowi) * 64 + gch],
                (AS3 unsigned int*)(&KL[buf][0][0] + (i * 256 + w * 64) * 8), 16, 0, 0);
            __builtin_amdgcn_global_load_lds(
                (const AS1 unsigned int*)&Vh[(size_t)(i * 32 + rowi) * VT_LD + kbase + gch],
                (AS3 unsigned int*)(&VL[buf][0][0] + (i * 256 + w * 64) * 8), 16, 0, 0);
        }
    };

    f32x4 lsumv = {};
    f32x4 ot[4] = {};

    stage(0, 0);
    __syncthreads();

    int cur = 0;
    for (int kt = 0; kt < 9; ++kt) {
        if (kt < 8) stage(cur ^ 1, (kt + 1) * 64);
        short8 kf0[4], kf1[4];
        #pragma unroll
        for (int f = 0; f < 4; ++f) {
            const unsigned short* kr = &KL[cur][f * 16 + c][0];
            kf0[f] = *(const short8*)&kr[((g    ) ^ (c & 7)) * 8];
            kf1[f] = *(const short8*)&kr[((4 + g) ^ (c & 7)) * 8];
        }
        f32x4 st[4];
        __builtin_amdgcn_s_setprio(1);
        #pragma unroll
        for (int f = 0; f < 4; ++f) {
            f32x4 z = {};
            z = MFMA(kf0[f], bq0, z);
            z = MFMA(kf1[f], bq1, z);
            st[f] = z;
        }
        __builtin_amdgcn_s_setprio(0);
        #pragma unroll
        for (int f = 0; f < 4; ++f) {
            float p0 = exp2f(fminf(st[f][0], 60.f));
            float p1 = exp2f(fminf(st[f][1], 60.f));
            float p2 = exp2f(fminf(st[f][2], 60.f));
            float p3 = exp2f(fminf(st[f][3], 60.f));
            lsumv[0] += p0; lsumv[1] += p1; lsumv[2] += p2; lsumv[3] += p3;
            uint2 pw;
            pw.x = cvt_pk_bf16(p0, p1);
            pw.y = cvt_pk_bf16(p2, p3);
            *(uint2*)&pt[w][c][f * 16 + g * 4] = pw;
        }
        __builtin_amdgcn_s_setprio(1);
        #pragma unroll
        for (int kk = 0; kk < 2; ++kk) {
            short8 bp = *(const short8*)&pt[w][c][kk * 32 + g * 8];
            #pragma unroll
            for (int df = 0; df < 4; ++df) {
                const unsigned short* vr = &VL[cur][df * 16 + c][0];
                short8 av = *(const short8*)&vr[((kk * 4 + g) ^ (c & 7)) * 8];
                ot[df] = MFMA(av, bp, ot[df]);
            }
        }
        __builtin_amdgcn_s_setprio(0);
        __syncthreads();
        cur ^= 1;
    }

    float lsum = (lsumv[0] + lsumv[1]) + (lsumv[2] + lsumv[3]);
    lsum += __shfl_xor(lsum, 16);
    lsum += __shfl_xor(lsum, 32);

    // tail: key 576 (scalar)
    {
        const unsigned short* kp = &Kh[(size_t)576 * 64];
        float dot = 0.f;
        #pragma unroll
        for (int jx = 0; jx < 8; ++jx) {
            dot += bf2f((unsigned short)bq0[jx]) * bf2f(kp[g * 8 + jx]);
            dot += bf2f((unsigned short)bq1[jx]) * bf2f(kp[32 + g * 8 + jx]);
        }
        dot += __shfl_xor(dot, 16);
        dot += __shfl_xor(dot, 32);
        float p = exp2f(fminf(dot, 60.f));
        lsum += p;
        #pragma unroll
        for (int df = 0; df < 4; ++df)
        #pragma unroll
        for (int e = 0; e < 4; ++e)
            ot[df][e] += p * bf2f(Vh[(size_t)(df * 16 + g * 4 + e) * VT_LD + 576]);
    }

    float inv = 1.0f / lsum;
    if (q < NTOK) {
        size_t orow = ((size_t)b * NTOK + q) * 768 + h * 64;
        #pragma unroll
        for (int df = 0; df < 4; ++df) {
            uint2 ov;
            ov.x = cvt_pk_bf16(ot[df][0] * inv, ot[df][1] * inv);
            ov.y = cvt_pk_bf16(ot[df][2] * inv, ot[df][3] * inv);
            *(uint2*)&Og[orow + df * 16 + g * 4] = ov;
        }
    }
}

// ---------------- launch ----------------
extern "C" void kernel_launch(void* const* d_in, const int* in_sizes, int n_in,
                              void* d_out, int out_size, void* d_ws, size_t ws_size,
                              hipStream_t stream) {
    const float* x      = (const float*)d_in[0];
    const float* W_qkv  = (const float*)d_in[1];
    const float* b_qkv  = (const float*)d_in[2];
    const float* W_proj = (const float*)d_in[3];
    const float* b_proj = (const float*)d_in[4];
    float* out = (float*)d_out;

    const int B = 32, N = 577, C = 768, H = 12;
    const int M = B * N;            // 18464

    char* ws = (char*)d_ws;
    size_t off = 0;
    auto alloc = [&](size_t bytes) {
        char* p = ws + off;
        off += (bytes + 255) & ~(size_t)255;
        return p;
    };
    unsigned short* xb    = (unsigned short*)alloc((size_t)M * C * 2);
    unsigned short* wqkvt = (unsigned short*)alloc((size_t)3 * C * C * 2);
    unsigned short* wprjt = (unsigned short*)alloc((size_t)C * C * 2);
    unsigned short* Qb    = (unsigned short*)alloc((size_t)B * H * N * 64 * 2);
    unsigned short* Kb    = (unsigned short*)alloc((size_t)B * H * N * 64 * 2);
    unsigned short* Vtb   = (unsigned short*)alloc((size_t)B * H * 64 * VT_LD * 2);
    unsigned short* attn  = xb;     // x_bf16 dead after QKV GEMM

    int n4 = M * C / 4;
    cvt_f32_bf16<<<dim3((n4 + 255) / 256), 256, 0, stream>>>(x, xb, n4);
    transpose_cvt<<<dim3(3 * C / 32, C / 32), 256, 0, stream>>>(W_qkv, wqkvt, C, 3 * C);
    transpose_cvt<<<dim3(C / 32, C / 32), 256, 0, stream>>>(W_proj, wprjt, C, C);

    // QKV: wave-private zero-barrier GEMM, 145 x 18 = 2610 blocks
    gemm_wp<0><<<dim3(145 * 18), 256, 0, stream>>>(
        xb, wqkvt, b_qkv, Qb, Kb, Vtb, nullptr, M, 18);

    attn_flash<<<dim3(3840), 256, 0, stream>>>(Qb, Kb, Vtb, attn);

    // proj: 128x128 tiles (proven), 145 x 6 = 870 blocks
    gemm128<1><<<dim3(6 * 145), 256, 0, stream>>>(
        attn, wprjt, b_proj, nullptr, nullptr, nullptr, out, M, C, 6);
}

// Round 13
// 273.471 us; speedup vs baseline: 1.2333x; 1.2333x over previous
//
#include <hip/hip_runtime.h>
#include <stdint.h>

typedef __attribute__((ext_vector_type(8))) short short8;
typedef __attribute__((ext_vector_type(4))) short short4v;
typedef __attribute__((ext_vector_type(4))) float f32x4;

#define MFMA(a,b,c) __builtin_amdgcn_mfma_f32_16x16x32_bf16((a),(b),(c),0,0,0)
#define QSCALE 0.18033688f   /* 0.125 * log2(e): softmax in exp2 domain */
#define VT_LD 584
#define NTOK 577
#define PT_LD 72
#define AS1 __attribute__((address_space(1)))
#define AS3 __attribute__((address_space(3)))

#define BARX() do { __builtin_amdgcn_sched_barrier(0); __builtin_amdgcn_s_barrier(); \
                    __builtin_amdgcn_sched_barrier(0); } while (0)
#define VMC(N) do { __builtin_amdgcn_sched_barrier(0); \
                    asm volatile("s_waitcnt vmcnt(" #N ")" ::: "memory"); \
                    __builtin_amdgcn_sched_barrier(0); } while (0)

__device__ __forceinline__ unsigned short f2bf(float f) {
    unsigned int u = __float_as_uint(f);
    u += 0x7fffu + ((u >> 16) & 1u);   // RNE
    return (unsigned short)(u >> 16);
}
__device__ __forceinline__ float bf2f(unsigned short u) {
    return __uint_as_float(((unsigned int)u) << 16);
}
__device__ __forceinline__ unsigned int cvt_pk_bf16(float lo, float hi) {
    unsigned int r;
    asm("v_cvt_pk_bf16_f32 %0, %1, %2" : "=v"(r) : "v"(lo), "v"(hi));
    return r;
}

// ---------------- conversions ----------------
__global__ __launch_bounds__(256) void cvt_f32_bf16(const float* __restrict__ in,
                                                    unsigned short* __restrict__ out, int n4) {
    int i = blockIdx.x * 256 + threadIdx.x;
    if (i < n4) {
        float4 v = ((const float4*)in)[i];
        short4v s;
        s[0] = (short)f2bf(v.x); s[1] = (short)f2bf(v.y);
        s[2] = (short)f2bf(v.z); s[3] = (short)f2bf(v.w);
        ((short4v*)out)[i] = s;
    }
}

// in [R][C] f32 -> out [C][R] bf16   (R,C multiples of 32)
__global__ __launch_bounds__(256) void transpose_cvt(const float* __restrict__ in,
                                                     unsigned short* __restrict__ out,
                                                     int R, int C) {
    __shared__ float tile[32][33];
    int c0 = blockIdx.x * 32, r0 = blockIdx.y * 32;
    int lc = threadIdx.x & 31, lr = threadIdx.x >> 5;
    #pragma unroll
    for (int i = 0; i < 4; ++i) {
        int r = lr + i * 8;
        tile[r][lc] = in[(size_t)(r0 + r) * C + c0 + lc];
    }
    __syncthreads();
    #pragma unroll
    for (int i = 0; i < 4; ++i) {
        int r = lr + i * 8;
        out[(size_t)(c0 + r) * R + r0 + lc] = f2bf(tile[lc][r]);
    }
}

// ---- GEMM (QKV): 256x256, BK=64, 8 waves, m201-style 8-phase counted-vmcnt ----
// Tile t lives in buf t&1. Per iteration (tiles u=2i buf0, v=2i+1 buf1), 8 phases:
//   P1: rd a0,b0(u)  | stage (v,B0)    P5: rd a0,b0(v)  | stage (u+2,B0)
//   P2: rd a1(u)     | stage (v,B1)    P6: rd a1(v)     | stage (u+2,B1)
//   P3: rd b1(u)     | stage (u+2,A0)  P7: rd b1(v)     | stage (v+2,A0)
//   P4:              | stage (u+2,A1)  P8:              | stage (v+2,A1)
// each phase: {reads|stage} -> barrier -> 16 MFMA -> barrier; vmcnt(4) ONLY at P4/P8
// (per-wave audit: the 4 older stages needed next phase land; newest 2 stay in flight).
template<int EPI>
__global__ __launch_bounds__(512, 1) void gemm8p(
    const unsigned short* __restrict__ A,
    const unsigned short* __restrict__ Bt,
    const float* __restrict__ bias,
    unsigned short* __restrict__ q_out, unsigned short* __restrict__ k_out,
    unsigned short* __restrict__ vt_out, float* __restrict__ f_out,
    int M, int NB)
{
    __shared__ __align__(16) unsigned short As[2][2][128 * 64];   // [buf][half] 64 KB
    __shared__ __align__(16) unsigned short Bs[2][2][128 * 64];   // 64 KB

    const int nwg = gridDim.x, orig = blockIdx.x;
    const int qd = nwg >> 3, r8 = nwg & 7;
    const int xcd = orig & 7, j0 = orig >> 3;
    const int wg = (xcd < r8 ? xcd * (qd + 1) : r8 * (qd + 1) + (xcd - r8) * qd) + j0;
    const int bx = wg % NB, by = wg / NB;
    const int m0 = by * 256, n0 = bx * 256;

    const int t = threadIdx.x, lane = t & 63, w = t >> 6;
    const int g = lane >> 4, c = lane & 15;
    const int wr = w >> 2, wcn = w & 3;                 // 2M x 4N wave grid
    const int srow = lane >> 3;                         // 0..7
    const int csw = (((lane & 7) ^ srow) * 8);          // pre-swizzled source chunk

    f32x4 acc[8][4] = {};

    auto stageA = [&](int buf, int half, int kt) {      // one 128x64 half-tile, 2 loads/thread
        #pragma unroll
        for (int jld = 0; jld < 2; ++jld) {
            int rr = (jld * 8 + w) * 8 + srow;
            int grow = m0 + half * 128 + rr;
            grow = grow < M ? grow : M - 1;
            __builtin_amdgcn_global_load_lds(
                (const AS1 unsigned int*)&A[(size_t)grow * 768 + kt * 64 + csw],
                (AS3 unsigned int*)&As[buf][half][(jld * 8 + w) * 512], 16, 0, 0);
        }
    };
    auto stageB = [&](int buf, int half, int kt) {
        #pragma unroll
        for (int jld = 0; jld < 2; ++jld) {
            int rr = (jld * 8 + w) * 8 + srow;
            int grow = n0 + half * 128 + rr;
            __builtin_amdgcn_global_load_lds(
                (const AS1 unsigned int*)&Bt[(size_t)grow * 768 + kt * 64 + csw],
                (AS3 unsigned int*)&Bs[buf][half][(jld * 8 + w) * 512], 16, 0, 0);
        }
    };
    auto rdA = [&](int buf, int kkc, short8* dst) {     // 8 ds_read_b128
        #pragma unroll
        for (int mf = 0; mf < 8; ++mf)
            dst[mf] = *(const short8*)&As[buf][wr][(mf * 16 + c) * 64 + (((kkc + g) ^ (c & 7)) * 8)];
    };
    auto rdB = [&](int buf, int kkc, short8* dst) {     // 4 ds_read_b128
        #pragma unroll
        for (int nf = 0; nf < 4; ++nf)
            dst[nf] = *(const short8*)&Bs[buf][wcn >> 1][((wcn & 1) * 64 + nf * 16 + c) * 64 + (((kkc + g) ^ (c & 7)) * 8)];
    };
    auto mm = [&](const short8* afr, int off, const short8* bfr) {   // 16 MFMA
        __builtin_amdgcn_s_setprio(1);
        #pragma unroll
        for (int mf = 0; mf < 4; ++mf)
        #pragma unroll
        for (int nf = 0; nf < 4; ++nf)
            acc[off + mf][nf] = MFMA(afr[off + mf], bfr[nf], acc[off + mf][nf]);
        __builtin_amdgcn_s_setprio(0);
    };

    short8 a0[8], a1[8], b0[4], b1[4];

    // prologue: tile0 complete + tile1 A-halves (6 stages = 12 loads)
    stageA(0, 0, 0); stageA(0, 1, 0);
    stageB(0, 0, 0); stageB(0, 1, 0);
    stageA(1, 0, 1); stageA(1, 1, 1);
    VMC(4);                                   // tile0 landed; tile1-A in flight
    __builtin_amdgcn_s_barrier();
    __builtin_amdgcn_sched_barrier(0);

    #pragma unroll
    for (int i = 0; i < 6; ++i) {
        const int u = 2 * i, v = u + 1;
        const bool pf = (i < 5);
        // ---- P1 ----
        rdA(0, 0, a0); rdB(0, 0, b0);
        stageB(1, 0, v);
        BARX(); mm(a0, 0, b0); BARX();
        // ---- P2 ----
        rdA(0, 4, a1);
        stageB(1, 1, v);
        BARX(); mm(a0, 4, b0); BARX();
        // ---- P3 ----
        rdB(0, 4, b1);
        if (pf) stageA(0, 0, u + 2);
        BARX(); mm(a1, 0, b1); BARX();
        // ---- P4 ----
        if (pf) stageA(0, 1, u + 2);
        BARX(); mm(a1, 4, b1);
        if (pf) { VMC(4); } else { VMC(0); }   // (v,B0/B1) + older landed
        __builtin_amdgcn_s_barrier();
        __builtin_amdgcn_sched_barrier(0);
        // ---- P5 ----
        rdA(1, 0, a0); rdB(1, 0, b0);
        if (pf) stageB(0, 0, u + 2);
        BARX(); mm(a0, 0, b0); BARX();
        // ---- P6 ----
        rdA(1, 4, a1);
        if (pf) stageB(0, 1, u + 2);
        BARX(); mm(a0, 4, b0); BARX();
        // ---- P7 ----
        rdB(1, 4, b1);
        if (pf) stageA(1, 0, v + 2);
        BARX(); mm(a1, 0, b1); BARX();
        // ---- P8 ----
        if (pf) stageA(1, 1, v + 2);
        BARX(); mm(a1, 4, b1);
        if (pf) { VMC(4); }                    // (u+2) complete; (v+2,A) in flight
        __builtin_amdgcn_s_barrier();
        __builtin_amdgcn_sched_barrier(0);
    }

    #pragma unroll
    for (int mf = 0; mf < 8; ++mf)
    #pragma unroll
    for (int nf = 0; nf < 4; ++nf) {
        int n = n0 + wcn * 64 + nf * 16 + c;
        float bv = bias[n];
        #pragma unroll
        for (int e = 0; e < 4; ++e) {
            int m = m0 + wr * 128 + mf * 16 + g * 4 + e;
            if (m >= M) continue;
            float v = acc[mf][nf][e] + bv;
            if (EPI == 0) {
                int which = n / 768;
                int rr = n - which * 768;
                int h = rr >> 6, d = rr & 63;
                int b = m / 577, tok = m - b * 577;
                int bh = b * 12 + h;
                if (which == 0)      q_out[((size_t)bh * 577 + tok) * 64 + d] = f2bf(v * QSCALE);
                else if (which == 1) k_out[((size_t)bh * 577 + tok) * 64 + d] = f2bf(v);
                else                 vt_out[((size_t)bh * 64 + d) * VT_LD + tok] = f2bf(v);
            } else {
                f_out[(size_t)m * 768 + n] = v;
            }
        }
    }
}

// ---- GEMM B (proj): R6 128x128 single-buffer 2-phase (proven) ----
template<int EPI>
__global__ __launch_bounds__(256) void gemm128(
    const unsigned short* __restrict__ A,
    const unsigned short* __restrict__ Bt,
    const float* __restrict__ bias,
    unsigned short* __restrict__ q_out, unsigned short* __restrict__ k_out,
    unsigned short* __restrict__ vt_out, float* __restrict__ f_out,
    int M, int K, int NB)
{
    __shared__ __align__(16) unsigned short As[128 * 64];
    __shared__ __align__(16) unsigned short Bs[128 * 64];

    const int nwg = gridDim.x, orig = blockIdx.x;
    const int qd = nwg >> 3, r = nwg & 7;
    const int xcd = orig & 7, j = orig >> 3;
    const int wg = (xcd < r ? xcd * (qd + 1) : r * (qd + 1) + (xcd - r) * qd) + j;
    const int bx = wg % NB, by = wg / NB;
    const int m0 = by * 128, n0 = bx * 128;

    const int t = threadIdx.x, lane = t & 63, w = t >> 6;
    const int g = lane >> 4, c = lane & 15;
    const int wr = w >> 1, wc = w & 1;
    const int rowi = t >> 3;
    const int csw = (((t & 7) ^ (rowi & 7)) * 8);

    f32x4 acc[4][4] = {};

    for (int k0 = 0; k0 < K; k0 += 64) {
        #pragma unroll
        for (int i = 0; i < 4; ++i) {
            int row = i * 32 + rowi;
            int ra = m0 + row; ra = ra < M ? ra : M - 1;
            __builtin_amdgcn_global_load_lds(
                (const AS1 unsigned int*)&A[(size_t)ra * K + k0 + csw],
                (AS3 unsigned int*)&As[(i * 256 + w * 64) * 8], 16, 0, 0);
            __builtin_amdgcn_global_load_lds(
                (const AS1 unsigned int*)&Bt[(size_t)(n0 + row) * K + k0 + csw],
                (AS3 unsigned int*)&Bs[(i * 256 + w * 64) * 8], 16, 0, 0);
        }
        __syncthreads();
        #pragma unroll
        for (int kk = 0; kk < 2; ++kk) {
            short8 af[4], bfr[4];
            #pragma unroll
            for (int mf = 0; mf < 4; ++mf) {
                int rr = wr * 64 + mf * 16 + c;
                af[mf] = *(const short8*)&As[rr * 64 + (((kk * 4 + g) ^ (c & 7)) * 8)];
            }
            #pragma unroll
            for (int nf = 0; nf < 4; ++nf) {
                int rr = wc * 64 + nf * 16 + c;
                bfr[nf] = *(const short8*)&Bs[rr * 64 + (((kk * 4 + g) ^ (c & 7)) * 8)];
            }
            __builtin_amdgcn_s_setprio(1);
            #pragma unroll
            for (int mf = 0; mf < 4; ++mf)
            #pragma unroll
            for (int nf = 0; nf < 4; ++nf)
                acc[mf][nf] = MFMA(af[mf], bfr[nf], acc[mf][nf]);
            __builtin_amdgcn_s_setprio(0);
        }
        __syncthreads();
    }

    #pragma unroll
    for (int mf = 0; mf < 4; ++mf)
    #pragma unroll
    for (int nf = 0; nf < 4; ++nf) {
        int n = n0 + wc * 64 + nf * 16 + c;
        float bv = bias[n];
        #pragma unroll
        for (int e = 0; e < 4; ++e) {
            int m = m0 + wr * 64 + mf * 16 + g * 4 + e;
            if (m >= M) continue;
            float v = acc[mf][nf][e] + bv;
            if (EPI == 0) {
                int which = n / 768;
                int rr = n - which * 768;
                int h = rr >> 6, d = rr & 63;
                int b = m / 577, tok = m - b * 577;
                int bh = b * 12 + h;
                if (which == 0)      q_out[((size_t)bh * 577 + tok) * 64 + d] = f2bf(v * QSCALE);
                else if (which == 1) k_out[((size_t)bh * 577 + tok) * 64 + d] = f2bf(v);
                else                 vt_out[((size_t)bh * 64 + d) * VT_LD + tok] = f2bf(v);
            } else {
                f_out[(size_t)m * 768 + n] = v;
            }
        }
    }
}

// ---------------- flash attention: LDS-staged K/V (2-phase dbuf), fixed-shift softmax --
__global__ __launch_bounds__(256, 3) void attn_flash(
    const unsigned short* __restrict__ Qg,
    const unsigned short* __restrict__ Kg,
    const unsigned short* __restrict__ Vtg,
    unsigned short* __restrict__ Og)
{
    __shared__ __align__(16) unsigned short KL[2][64][64];
    __shared__ __align__(16) unsigned short VL[2][64][64];
    __shared__ __align__(16) unsigned short pt[4][16][PT_LD];

    const int nwg = gridDim.x, orig = blockIdx.x;
    const int qd = nwg >> 3, jj8 = nwg & 7;
    const int xcd = orig & 7, jj = orig >> 3;
    const int wgid = (xcd < jj8 ? xcd * (qd + 1) : jj8 * (qd + 1) + (xcd - jj8) * qd) + jj;
    const int qt = wgid % 10;
    const int bh = wgid / 10;
    const int b = bh / 12, h = bh - b * 12;
    const int t = threadIdx.x, w = t >> 6, lane = t & 63;
    const int g = lane >> 4, c = lane & 15;
    const int rowi = t >> 3;                        // 0..31
    const int gch = ((t & 7) ^ (rowi & 7)) * 8;     // pre-swizzled source chunk

    const unsigned short* Qh = Qg + (size_t)bh * NTOK * 64;
    const unsigned short* Kh = Kg + (size_t)bh * NTOK * 64;
    const unsigned short* Vh = Vtg + (size_t)bh * 64 * VT_LD;

    const int q = qt * 64 + w * 16 + c;
    const int qc = q < NTOK ? q : NTOK - 1;

    short8 bq0 = *(const short8*)&Qh[(size_t)qc * 64 +      g * 8];
    short8 bq1 = *(const short8*)&Qh[(size_t)qc * 64 + 32 + g * 8];

    auto stage = [&](int buf, int kbase) {
        #pragma unroll
        for (int i = 0; i < 2; ++i) {
            __builtin_amdgcn_global_load_lds(
                (const AS1 unsigned int*)&Kh[(size_t)(kbase + i * 32 + rowi) * 64 + gch],
                (AS3 unsigned int*)(&KL[buf][0][0] + (i * 256 + w * 64) * 8), 16, 0, 0);
            __builtin_amdgcn_global_load_lds(
                (const AS1 unsigned int*)&Vh[(size_t)(i * 32 + rowi) * VT_LD + kbase + gch],
                (AS3 unsigned int*)(&VL[buf][0][0] + (i * 256 + w * 64) * 8), 16, 0, 0);
        }
    };

    f32x4 lsumv = {};
    f32x4 ot[4] = {};

    stage(0, 0);
    __syncthreads();

    int cur = 0;
    for (int kt = 0; kt < 9; ++kt) {
        if (kt < 8) stage(cur ^ 1, (kt + 1) * 64);
        short8 kf0[4], kf1[4];
        #pragma unroll
        for (int f = 0; f < 4; ++f) {
            const unsigned short* kr = &KL[cur][f * 16 + c][0];
            kf0[f] = *(const short8*)&kr[((g    ) ^ (c & 7)) * 8];
            kf1[f] = *(const short8*)&kr[((4 + g) ^ (c & 7)) * 8];
        }
        f32x4 st[4];
        __builtin_amdgcn_s_setprio(1);
        #pragma unroll
        for (int f = 0; f < 4; ++f) {
            f32x4 z = {};
            z = MFMA(kf0[f], bq0, z);
            z = MFMA(kf1[f], bq1, z);
            st[f] = z;
        }
        __builtin_amdgcn_s_setprio(0);
        #pragma unroll
        for (int f = 0; f < 4; ++f) {
            float p0 = exp2f(fminf(st[f][0], 60.f));
            float p1 = exp2f(fminf(st[f][1], 60.f));
            float p2 = exp2f(fminf(st[f][2], 60.f));
            float p3 = exp2f(fminf(st[f][3], 60.f));
            lsumv[0] += p0; lsumv[1] += p1; lsumv[2] += p2; lsumv[3] += p3;
            uint2 pw;
            pw.x = cvt_pk_bf16(p0, p1);
            pw.y = cvt_pk_bf16(p2, p3);
            *(uint2*)&pt[w][c][f * 16 + g * 4] = pw;
        }
        __builtin_amdgcn_s_setprio(1);
        #pragma unroll
        for (int kk = 0; kk < 2; ++kk) {
            short8 bp = *(const short8*)&pt[w][c][kk * 32 + g * 8];
            #pragma unroll
            for (int df = 0; df < 4; ++df) {
                const unsigned short* vr = &VL[cur][df * 16 + c][0];
                short8 av = *(const short8*)&vr[((kk * 4 + g) ^ (c & 7)) * 8];
                ot[df] = MFMA(av, bp, ot[df]);
            }
        }
        __builtin_amdgcn_s_setprio(0);
        __syncthreads();
        cur ^= 1;
    }

    float lsum = (lsumv[0] + lsumv[1]) + (lsumv[2] + lsumv[3]);
    lsum += __shfl_xor(lsum, 16);
    lsum += __shfl_xor(lsum, 32);

    // tail: key 576 (scalar)
    {
        const unsigned short* kp = &Kh[(size_t)576 * 64];
        float dot = 0.f;
        #pragma unroll
        for (int jx = 0; jx < 8; ++jx) {
            dot += bf2f((unsigned short)bq0[jx]) * bf2f(kp[g * 8 + jx]);
            dot += bf2f((unsigned short)bq1[jx]) * bf2f(kp[32 + g * 8 + jx]);
        }
        dot += __shfl_xor(dot, 16);
        dot += __shfl_xor(dot, 32);
        float p = exp2f(fminf(dot, 60.f));
        lsum += p;
        #pragma unroll
        for (int df = 0; df < 4; ++df)
        #pragma unroll
        for (int e = 0; e < 4; ++e)
            ot[df][e] += p * bf2f(Vh[(size_t)(df * 16 + g * 4 + e) * VT_LD + 576]);
    }

    float inv = 1.0f / lsum;
    if (q < NTOK) {
        size_t orow = ((size_t)b * NTOK + q) * 768 + h * 64;
        #pragma unroll
        for (int df = 0; df < 4; ++df) {
            uint2 ov;
            ov.x = cvt_pk_bf16(ot[df][0] * inv, ot[df][1] * inv);
            ov.y = cvt_pk_bf16(ot[df][2] * inv, ot[df][3] * inv);
            *(uint2*)&Og[orow + df * 16 + g * 4] = ov;
        }
    }
}

// ---------------- launch ----------------
extern "C" void kernel_launch(void* const* d_in, const int* in_sizes, int n_in,
                              void* d_out, int out_size, void* d_ws, size_t ws_size,
                              hipStream_t stream) {
    const float* x      = (const float*)d_in[0];
    const float* W_qkv  = (const float*)d_in[1];
    const float* b_qkv  = (const float*)d_in[2];
    const float* W_proj = (const float*)d_in[3];
    const float* b_proj = (const float*)d_in[4];
    float* out = (float*)d_out;

    const int B = 32, N = 577, C = 768, H = 12;
    const int M = B * N;            // 18464

    char* ws = (char*)d_ws;
    size_t off = 0;
    auto alloc = [&](size_t bytes) {
        char* p = ws + off;
        off += (bytes + 255) & ~(size_t)255;
        return p;
    };
    unsigned short* xb    = (unsigned short*)alloc((size_t)M * C * 2);
    unsigned short* wqkvt = (unsigned short*)alloc((size_t)3 * C * C * 2);
    unsigned short* wprjt = (unsigned short*)alloc((size_t)C * C * 2);
    unsigned short* Qb    = (unsigned short*)alloc((size_t)B * H * N * 64 * 2);
    unsigned short* Kb    = (unsigned short*)alloc((size_t)B * H * N * 64 * 2);
    unsigned short* Vtb   = (unsigned short*)alloc((size_t)B * H * 64 * VT_LD * 2);
    unsigned short* attn  = xb;     // x_bf16 dead after QKV GEMM

    int n4 = M * C / 4;
    cvt_f32_bf16<<<dim3((n4 + 255) / 256), 256, 0, stream>>>(x, xb, n4);
    transpose_cvt<<<dim3(3 * C / 32, C / 32), 256, 0, stream>>>(W_qkv, wqkvt, C, 3 * C);
    transpose_cvt<<<dim3(C / 32, C / 32), 256, 0, stream>>>(W_proj, wprjt, C, C);

    // QKV: 8-phase 256x256, 73 x 9 = 657 blocks
    gemm8p<0><<<dim3(73 * 9), 512, 0, stream>>>(
        xb, wqkvt, b_qkv, Qb, Kb, Vtb, nullptr, M, 9);

    attn_flash<<<dim3(3840), 256, 0, stream>>>(Qb, Kb, Vtb, attn);

    // proj: 128x128 tiles (proven), 145 x 6 = 870 blocks
    gemm128<1><<<dim3(6 * 145), 256, 0, stream>>>(
        attn, wprjt, b_proj, nullptr, nullptr, nullptr, out, M, C, 6);
}

// Round 14
// 225.715 us; speedup vs baseline: 1.4942x; 1.2116x over previous
//
#include <hip/hip_runtime.h>
#include <stdint.h>

typedef __attribute__((ext_vector_type(8))) short short8;
typedef __attribute__((ext_vector_type(4))) short short4v;
typedef __attribute__((ext_vector_type(4))) float f32x4;
typedef uint2 __attribute__((aligned(2))) uint2a2;   // unaligned-safe 8B store

#define MFMA(a,b,c) __builtin_amdgcn_mfma_f32_16x16x32_bf16((a),(b),(c),0,0,0)
#define QSCALE 0.18033688f   /* 0.125 * log2(e): softmax in exp2 domain */
#define VT_LD 584
#define NTOK 577
#define PT_LD 72
#define AS1 __attribute__((address_space(1)))
#define AS3 __attribute__((address_space(3)))

__device__ __forceinline__ unsigned short f2bf(float f) {
    unsigned int u = __float_as_uint(f);
    u += 0x7fffu + ((u >> 16) & 1u);   // RNE
    return (unsigned short)(u >> 16);
}
__device__ __forceinline__ float bf2f(unsigned short u) {
    return __uint_as_float(((unsigned int)u) << 16);
}
__device__ __forceinline__ unsigned int cvt_pk_bf16(float lo, float hi) {
    unsigned int r;
    asm("v_cvt_pk_bf16_f32 %0, %1, %2" : "=v"(r) : "v"(lo), "v"(hi));
    return r;
}

// ---------------- conversions ----------------
__global__ __launch_bounds__(256) void cvt_f32_bf16(const float* __restrict__ in,
                                                    unsigned short* __restrict__ out, int n4) {
    int i = blockIdx.x * 256 + threadIdx.x;
    if (i < n4) {
        float4 v = ((const float4*)in)[i];
        short4v s;
        s[0] = (short)f2bf(v.x); s[1] = (short)f2bf(v.y);
        s[2] = (short)f2bf(v.z); s[3] = (short)f2bf(v.w);
        ((short4v*)out)[i] = s;
    }
}

// in [R][C] f32 -> out [C][R] bf16   (R,C multiples of 32)
__global__ __launch_bounds__(256) void transpose_cvt(const float* __restrict__ in,
                                                     unsigned short* __restrict__ out,
                                                     int R, int C) {
    __shared__ float tile[32][33];
    int c0 = blockIdx.x * 32, r0 = blockIdx.y * 32;
    int lc = threadIdx.x & 31, lr = threadIdx.x >> 5;
    #pragma unroll
    for (int i = 0; i < 4; ++i) {
        int r = lr + i * 8;
        tile[r][lc] = in[(size_t)(r0 + r) * C + c0 + lc];
    }
    __syncthreads();
    #pragma unroll
    for (int i = 0; i < 4; ++i) {
        int r = lr + i * 8;
        out[(size_t)(c0 + r) * R + r0 + lc] = f2bf(tile[lc][r]);
    }
}

// ---- GEMM A (QKV): 256x128 tile, 512 thr (4Mx2N waves), single-buffer 2-phase ----
// R10-proven skeleton (best measured). V^T epilogue vectorized: 4 consecutive tokens
// at fixed d -> one 8B packed store (scalar fallback at batch/M edges).
__global__ __launch_bounds__(512) void gemm256x128(
    const unsigned short* __restrict__ A,
    const unsigned short* __restrict__ Bt,
    const float* __restrict__ bias,
    unsigned short* __restrict__ q_out, unsigned short* __restrict__ k_out,
    unsigned short* __restrict__ vt_out,
    int M, int NB)
{
    __shared__ __align__(16) unsigned short As[256 * 64];
    __shared__ __align__(16) unsigned short Bs[128 * 64];

    const int nwg = gridDim.x, orig = blockIdx.x;
    const int qd = nwg >> 3, r8 = nwg & 7;
    const int xcd = orig & 7, j = orig >> 3;
    const int wg = (xcd < r8 ? xcd * (qd + 1) : r8 * (qd + 1) + (xcd - r8) * qd) + j;
    const int bx = wg % NB, by = wg / NB;
    const int m0 = by * 256, n0 = bx * 128;

    const int t = threadIdx.x, lane = t & 63, w = t >> 6;
    const int g = lane >> 4, c = lane & 15;
    const int wr = w >> 1, wcn = w & 1;            // 4 x 2 wave grid
    const int srow = t >> 3;                       // 0..63
    const int csw = (((t & 7) ^ (srow & 7)) * 8);  // pre-swizzled source chunk

    f32x4 acc[4][4] = {};

    for (int k0 = 0; k0 < 768; k0 += 64) {
        #pragma unroll
        for (int i = 0; i < 4; ++i) {              // A: 256 rows in 4 passes
            int row = i * 64 + srow;
            int ra = m0 + row; ra = ra < M ? ra : M - 1;
            __builtin_amdgcn_global_load_lds(
                (const AS1 unsigned int*)&A[(size_t)ra * 768 + k0 + csw],
                (AS3 unsigned int*)&As[i * 4096 + w * 512], 16, 0, 0);
        }
        #pragma unroll
        for (int i = 0; i < 2; ++i) {              // B: 128 rows in 2 passes
            int row = i * 64 + srow;
            __builtin_amdgcn_global_load_lds(
                (const AS1 unsigned int*)&Bt[(size_t)(n0 + row) * 768 + k0 + csw],
                (AS3 unsigned int*)&Bs[i * 4096 + w * 512], 16, 0, 0);
        }
        __syncthreads();
        #pragma unroll
        for (int kk = 0; kk < 2; ++kk) {
            short8 af[4], bfv[4];
            #pragma unroll
            for (int mf = 0; mf < 4; ++mf) {
                int rr = wr * 64 + mf * 16 + c;
                af[mf] = *(const short8*)&As[rr * 64 + (((kk * 4 + g) ^ (c & 7)) * 8)];
            }
            #pragma unroll
            for (int nf = 0; nf < 4; ++nf) {
                int rr = wcn * 64 + nf * 16 + c;
                bfv[nf] = *(const short8*)&Bs[rr * 64 + (((kk * 4 + g) ^ (c & 7)) * 8)];
            }
            __builtin_amdgcn_s_setprio(1);
            #pragma unroll
            for (int mf = 0; mf < 4; ++mf)
            #pragma unroll
            for (int nf = 0; nf < 4; ++nf)
                acc[mf][nf] = MFMA(af[mf], bfv[nf], acc[mf][nf]);
            __builtin_amdgcn_s_setprio(0);
        }
        __syncthreads();
    }

    #pragma unroll
    for (int mf = 0; mf < 4; ++mf)
    #pragma unroll
    for (int nf = 0; nf < 4; ++nf) {
        int n = n0 + wcn * 64 + nf * 16 + c;
        float bv = bias[n];
        int which = n / 768;
        int rr = n - which * 768;
        int h = rr >> 6, d = rr & 63;
        int mb = m0 + wr * 64 + mf * 16 + g * 4;      // first of 4 consecutive m
        if (which == 2) {
            int b0v = mb / 577, tok0 = mb - b0v * 577;
            if (mb + 3 < M && tok0 <= 573) {           // all 4 tokens in one batch
                int bh = b0v * 12 + h;
                uint2 pw;
                pw.x = cvt_pk_bf16(acc[mf][nf][0] + bv, acc[mf][nf][1] + bv);
                pw.y = cvt_pk_bf16(acc[mf][nf][2] + bv, acc[mf][nf][3] + bv);
                *(uint2a2*)&vt_out[((size_t)bh * 64 + d) * VT_LD + tok0] = pw;
            } else {
                #pragma unroll
                for (int e = 0; e < 4; ++e) {
                    int m = mb + e;
                    if (m >= M) continue;
                    int b = m / 577, tok = m - b * 577;
                    vt_out[((size_t)(b * 12 + h) * 64 + d) * VT_LD + tok] =
                        f2bf(acc[mf][nf][e] + bv);
                }
            }
        } else {
            #pragma unroll
            for (int e = 0; e < 4; ++e) {
                int m = mb + e;
                if (m >= M) continue;
                int b = m / 577, tok = m - b * 577;
                int bh = b * 12 + h;
                if (which == 0)
                    q_out[((size_t)bh * 577 + tok) * 64 + d] = f2bf((acc[mf][nf][e] + bv) * QSCALE);
                else
                    k_out[((size_t)bh * 577 + tok) * 64 + d] = f2bf(acc[mf][nf][e] + bv);
            }
        }
    }
}

// ---- GEMM B (proj): R6 128x128 single-buffer 2-phase (proven) ----
__global__ __launch_bounds__(256) void gemm128proj(
    const unsigned short* __restrict__ A,
    const unsigned short* __restrict__ Bt,
    const float* __restrict__ bias,
    float* __restrict__ f_out,
    int M, int K, int NB)
{
    __shared__ __align__(16) unsigned short As[128 * 64];
    __shared__ __align__(16) unsigned short Bs[128 * 64];

    const int nwg = gridDim.x, orig = blockIdx.x;
    const int qd = nwg >> 3, r = nwg & 7;
    const int xcd = orig & 7, j = orig >> 3;
    const int wg = (xcd < r ? xcd * (qd + 1) : r * (qd + 1) + (xcd - r) * qd) + j;
    const int bx = wg % NB, by = wg / NB;
    const int m0 = by * 128, n0 = bx * 128;

    const int t = threadIdx.x, lane = t & 63, w = t >> 6;
    const int g = lane >> 4, c = lane & 15;
    const int wr = w >> 1, wc = w & 1;
    const int rowi = t >> 3;
    const int csw = (((t & 7) ^ (rowi & 7)) * 8);

    f32x4 acc[4][4] = {};

    for (int k0 = 0; k0 < K; k0 += 64) {
        #pragma unroll
        for (int i = 0; i < 4; ++i) {
            int row = i * 32 + rowi;
            int ra = m0 + row; ra = ra < M ? ra : M - 1;
            __builtin_amdgcn_global_load_lds(
                (const AS1 unsigned int*)&A[(size_t)ra * K + k0 + csw],
                (AS3 unsigned int*)&As[(i * 256 + w * 64) * 8], 16, 0, 0);
            __builtin_amdgcn_global_load_lds(
                (const AS1 unsigned int*)&Bt[(size_t)(n0 + row) * K + k0 + csw],
                (AS3 unsigned int*)&Bs[(i * 256 + w * 64) * 8], 16, 0, 0);
        }
        __syncthreads();
        #pragma unroll
        for (int kk = 0; kk < 2; ++kk) {
            short8 af[4], bfr[4];
            #pragma unroll
            for (int mf = 0; mf < 4; ++mf) {
                int rr = wr * 64 + mf * 16 + c;
                af[mf] = *(const short8*)&As[rr * 64 + (((kk * 4 + g) ^ (c & 7)) * 8)];
            }
            #pragma unroll
            for (int nf = 0; nf < 4; ++nf) {
                int rr = wc * 64 + nf * 16 + c;
                bfr[nf] = *(const short8*)&Bs[rr * 64 + (((kk * 4 + g) ^ (c & 7)) * 8)];
            }
            __builtin_amdgcn_s_setprio(1);
            #pragma unroll
            for (int mf = 0; mf < 4; ++mf)
            #pragma unroll
            for (int nf = 0; nf < 4; ++nf)
                acc[mf][nf] = MFMA(af[mf], bfr[nf], acc[mf][nf]);
            __builtin_amdgcn_s_setprio(0);
        }
        __syncthreads();
    }

    #pragma unroll
    for (int mf = 0; mf < 4; ++mf)
    #pragma unroll
    for (int nf = 0; nf < 4; ++nf) {
        int n = n0 + wc * 64 + nf * 16 + c;
        float bv = bias[n];
        #pragma unroll
        for (int e = 0; e < 4; ++e) {
            int m = m0 + wr * 64 + mf * 16 + g * 4 + e;
            if (m >= M) continue;
            f_out[(size_t)m * 768 + n] = acc[mf][nf][e] + bv;
        }
    }
}

// ---------------- flash attention: LDS-staged K/V (2-phase dbuf), fixed-shift softmax --
__global__ __launch_bounds__(256, 3) void attn_flash(
    const unsigned short* __restrict__ Qg,
    const unsigned short* __restrict__ Kg,
    const unsigned short* __restrict__ Vtg,
    unsigned short* __restrict__ Og)
{
    __shared__ __align__(16) unsigned short KL[2][64][64];
    __shared__ __align__(16) unsigned short VL[2][64][64];
    __shared__ __align__(16) unsigned short pt[4][16][PT_LD];

    const int nwg = gridDim.x, orig = blockIdx.x;
    const int qd = nwg >> 3, jj8 = nwg & 7;
    const int xcd = orig & 7, jj = orig >> 3;
    const int wgid = (xcd < jj8 ? xcd * (qd + 1) : jj8 * (qd + 1) + (xcd - jj8) * qd) + jj;
    const int qt = wgid % 10;
    const int bh = wgid / 10;
    const int b = bh / 12, h = bh - b * 12;
    const int t = threadIdx.x, w = t >> 6, lane = t & 63;
    const int g = lane >> 4, c = lane & 15;
    const int rowi = t >> 3;                        // 0..31
    const int gch = ((t & 7) ^ (rowi & 7)) * 8;     // pre-swizzled source chunk

    const unsigned short* Qh = Qg + (size_t)bh * NTOK * 64;
    const unsigned short* Kh = Kg + (size_t)bh * NTOK * 64;
    const unsigned short* Vh = Vtg + (size_t)bh * 64 * VT_LD;

    const int q = qt * 64 + w * 16 + c;
    const int qc = q < NTOK ? q : NTOK - 1;

    short8 bq0 = *(const short8*)&Qh[(size_t)qc * 64 +      g * 8];
    short8 bq1 = *(const short8*)&Qh[(size_t)qc * 64 + 32 + g * 8];

    auto stage = [&](int buf, int kbase) {
        #pragma unroll
        for (int i = 0; i < 2; ++i) {
            __builtin_amdgcn_global_load_lds(
                (const AS1 unsigned int*)&Kh[(size_t)(kbase + i * 32 + rowi) * 64 + gch],
                (AS3 unsigned int*)(&KL[buf][0][0] + (i * 256 + w * 64) * 8), 16, 0, 0);
            __builtin_amdgcn_global_load_lds(
                (const AS1 unsigned int*)&Vh[(size_t)(i * 32 + rowi) * VT_LD + kbase + gch],
                (AS3 unsigned int*)(&VL[buf][0][0] + (i * 256 + w * 64) * 8), 16, 0, 0);
        }
    };

    f32x4 lsumv = {};
    f32x4 ot[4] = {};

    stage(0, 0);
    __syncthreads();

    int cur = 0;
    for (int kt = 0; kt < 9; ++kt) {
        if (kt < 8) stage(cur ^ 1, (kt + 1) * 64);
        short8 kf0[4], kf1[4];
        #pragma unroll
        for (int f = 0; f < 4; ++f) {
            const unsigned short* kr = &KL[cur][f * 16 + c][0];
            kf0[f] = *(const short8*)&kr[((g    ) ^ (c & 7)) * 8];
            kf1[f] = *(const short8*)&kr[((4 + g) ^ (c & 7)) * 8];
        }
        f32x4 st[4];
        __builtin_amdgcn_s_setprio(1);
        #pragma unroll
        for (int f = 0; f < 4; ++f) {
            f32x4 z = {};
            z = MFMA(kf0[f], bq0, z);
            z = MFMA(kf1[f], bq1, z);
            st[f] = z;
        }
        __builtin_amdgcn_s_setprio(0);
        #pragma unroll
        for (int f = 0; f < 4; ++f) {
            float p0 = exp2f(fminf(st[f][0], 60.f));
            float p1 = exp2f(fminf(st[f][1], 60.f));
            float p2 = exp2f(fminf(st[f][2], 60.f));
            float p3 = exp2f(fminf(st[f][3], 60.f));
            lsumv[0] += p0; lsumv[1] += p1; lsumv[2] += p2; lsumv[3] += p3;
            uint2 pw;
            pw.x = cvt_pk_bf16(p0, p1);
            pw.y = cvt_pk_bf16(p2, p3);
            *(uint2*)&pt[w][c][f * 16 + g * 4] = pw;
        }
        __builtin_amdgcn_s_setprio(1);
        #pragma unroll
        for (int kk = 0; kk < 2; ++kk) {
            short8 bp = *(const short8*)&pt[w][c][kk * 32 + g * 8];
            #pragma unroll
            for (int df = 0; df < 4; ++df) {
                const unsigned short* vr = &VL[cur][df * 16 + c][0];
                short8 av = *(const short8*)&vr[((kk * 4 + g) ^ (c & 7)) * 8];
                ot[df] = MFMA(av, bp, ot[df]);
            }
        }
        __builtin_amdgcn_s_setprio(0);
        __syncthreads();
        cur ^= 1;
    }

    float lsum = (lsumv[0] + lsumv[1]) + (lsumv[2] + lsumv[3]);
    lsum += __shfl_xor(lsum, 16);
    lsum += __shfl_xor(lsum, 32);

    // tail: key 576 (scalar)
    {
        const unsigned short* kp = &Kh[(size_t)576 * 64];
        float dot = 0.f;
        #pragma unroll
        for (int jx = 0; jx < 8; ++jx) {
            dot += bf2f((unsigned short)bq0[jx]) * bf2f(kp[g * 8 + jx]);
            dot += bf2f((unsigned short)bq1[jx]) * bf2f(kp[32 + g * 8 + jx]);
        }
        dot += __shfl_xor(dot, 16);
        dot += __shfl_xor(dot, 32);
        float p = exp2f(fminf(dot, 60.f));
        lsum += p;
        #pragma unroll
        for (int df = 0; df < 4; ++df)
        #pragma unroll
        for (int e = 0; e < 4; ++e)
            ot[df][e] += p * bf2f(Vh[(size_t)(df * 16 + g * 4 + e) * VT_LD + 576]);
    }

    float inv = 1.0f / lsum;
    if (q < NTOK) {
        size_t orow = ((size_t)b * NTOK + q) * 768 + h * 64;
        #pragma unroll
        for (int df = 0; df < 4; ++df) {
            uint2 ov;
            ov.x = cvt_pk_bf16(ot[df][0] * inv, ot[df][1] * inv);
            ov.y = cvt_pk_bf16(ot[df][2] * inv, ot[df][3] * inv);
            *(uint2*)&Og[orow + df * 16 + g * 4] = ov;
        }
    }
}

// ---------------- launch ----------------
extern "C" void kernel_launch(void* const* d_in, const int* in_sizes, int n_in,
                              void* d_out, int out_size, void* d_ws, size_t ws_size,
                              hipStream_t stream) {
    const float* x      = (const float*)d_in[0];
    const float* W_qkv  = (const float*)d_in[1];
    const float* b_qkv  = (const float*)d_in[2];
    const float* W_proj = (const float*)d_in[3];
    const float* b_proj = (const float*)d_in[4];
    float* out = (float*)d_out;

    const int B = 32, N = 577, C = 768, H = 12;
    const int M = B * N;            // 18464

    char* ws = (char*)d_ws;
    size_t off = 0;
    auto alloc = [&](size_t bytes) {
        char* p = ws + off;
        off += (bytes + 255) & ~(size_t)255;
        return p;
    };
    unsigned short* xb    = (unsigned short*)alloc((size_t)M * C * 2);
    unsigned short* wqkvt = (unsigned short*)alloc((size_t)3 * C * C * 2);
    unsigned short* wprjt = (unsigned short*)alloc((size_t)C * C * 2);
    unsigned short* Qb    = (unsigned short*)alloc((size_t)B * H * N * 64 * 2);
    unsigned short* Kb    = (unsigned short*)alloc((size_t)B * H * N * 64 * 2);
    unsigned short* Vtb   = (unsigned short*)alloc((size_t)B * H * 64 * VT_LD * 2);
    unsigned short* attn  = xb;     // x_bf16 dead after QKV GEMM

    int n4 = M * C / 4;
    cvt_f32_bf16<<<dim3((n4 + 255) / 256), 256, 0, stream>>>(x, xb, n4);
    transpose_cvt<<<dim3(3 * C / 32, C / 32), 256, 0, stream>>>(W_qkv, wqkvt, C, 3 * C);
    transpose_cvt<<<dim3(C / 32, C / 32), 256, 0, stream>>>(W_proj, wprjt, C, C);

    // QKV: 256x128 tiles, 73 x 18 = 1314 blocks (R10-proven)
    gemm256x128<<<dim3(73 * 18), 512, 0, stream>>>(
        xb, wqkvt, b_qkv, Qb, Kb, Vtb, M, 18);

    attn_flash<<<dim3(3840), 256, 0, stream>>>(Qb, Kb, Vtb, attn);

    // proj: 128x128 tiles (proven), 145 x 6 = 870 blocks
    gemm128proj<<<dim3(6 * 145), 256, 0, stream>>>(
        attn, wprjt, b_proj, out, M, C, 6);
}

// Round 15
// 210.690 us; speedup vs baseline: 1.6008x; 1.0713x over previous
//
#include <hip/hip_runtime.h>
#include <stdint.h>

typedef __attribute__((ext_vector_type(8))) short short8;
typedef __attribute__((ext_vector_type(4))) short short4v;
typedef __attribute__((ext_vector_type(4))) float f32x4;
typedef uint2 __attribute__((aligned(2))) uint2a2;   // unaligned-safe 8B store

#define MFMA(a,b,c) __builtin_amdgcn_mfma_f32_16x16x32_bf16((a),(b),(c),0,0,0)
#define QSCALE 0.18033688f   /* 0.125 * log2(e): softmax in exp2 domain */
#define VT_LD 584
#define NTOK 577
#define PT_LD 72
#define AS1 __attribute__((address_space(1)))
#define AS3 __attribute__((address_space(3)))

__device__ __forceinline__ unsigned short f2bf(float f) {
    unsigned int u = __float_as_uint(f);
    u += 0x7fffu + ((u >> 16) & 1u);   // RNE
    return (unsigned short)(u >> 16);
}
__device__ __forceinline__ float bf2f(unsigned short u) {
    return __uint_as_float(((unsigned int)u) << 16);
}
__device__ __forceinline__ unsigned int cvt_pk_bf16(float lo, float hi) {
    unsigned int r;
    asm("v_cvt_pk_bf16_f32 %0, %1, %2" : "=v"(r) : "v"(lo), "v"(hi));
    return r;
}

// ---------------- fused prep: x->bf16 (13848 blk) | W_qkv^T (1728 blk) | W_proj^T (576) --
__global__ __launch_bounds__(256) void prep(
    const float* __restrict__ x, unsigned short* __restrict__ xb,
    const float* __restrict__ Wq, unsigned short* __restrict__ Wqt,
    const float* __restrict__ Wp, unsigned short* __restrict__ Wpt)
{
    __shared__ float tile[32][33];
    const int bid = blockIdx.x;
    if (bid < 13848) {                       // cvt: M*C/4 = 3545088 elems of float4
        int i = bid * 256 + threadIdx.x;
        float4 v = ((const float4*)x)[i];
        short4v s;
        s[0] = (short)f2bf(v.x); s[1] = (short)f2bf(v.y);
        s[2] = (short)f2bf(v.z); s[3] = (short)f2bf(v.w);
        ((short4v*)xb)[i] = s;
        return;
    }
    const float* in; unsigned short* out; int R, C, c0, r0;
    if (bid < 13848 + 1728) {                // W_qkv: [768][2304] -> [2304][768]
        int ib = bid - 13848;
        in = Wq; out = Wqt; R = 768; C = 2304;
        c0 = (ib % 72) * 32; r0 = (ib / 72) * 32;
    } else {                                 // W_proj: [768][768] -> [768][768]
        int ib = bid - 15576;
        in = Wp; out = Wpt; R = 768; C = 768;
        c0 = (ib % 24) * 32; r0 = (ib / 24) * 32;
    }
    int lc = threadIdx.x & 31, lr = threadIdx.x >> 5;
    #pragma unroll
    for (int i = 0; i < 4; ++i) {
        int r = lr + i * 8;
        tile[r][lc] = in[(size_t)(r0 + r) * C + c0 + lc];
    }
    __syncthreads();
    #pragma unroll
    for (int i = 0; i < 4; ++i) {
        int r = lr + i * 8;
        out[(size_t)(c0 + r) * R + r0 + lc] = f2bf(tile[lc][r]);
    }
}

// ---- GEMM: 256x128 tile, 512 thr (4Mx2N waves), single-buffer 2-phase (proven) ----
// EPI 0: QKV scatter (packed V^T stores). EPI 1: proj, fp32 out.
template<int EPI>
__global__ __launch_bounds__(512) void gemm256x128(
    const unsigned short* __restrict__ A,
    const unsigned short* __restrict__ Bt,
    const float* __restrict__ bias,
    unsigned short* __restrict__ q_out, unsigned short* __restrict__ k_out,
    unsigned short* __restrict__ vt_out, float* __restrict__ f_out,
    int M, int NB)
{
    __shared__ __align__(16) unsigned short As[256 * 64];
    __shared__ __align__(16) unsigned short Bs[128 * 64];

    const int nwg = gridDim.x, orig = blockIdx.x;
    const int qd = nwg >> 3, r8 = nwg & 7;
    const int xcd = orig & 7, j = orig >> 3;
    const int wg = (xcd < r8 ? xcd * (qd + 1) : r8 * (qd + 1) + (xcd - r8) * qd) + j;
    const int bx = wg % NB, by = wg / NB;
    const int m0 = by * 256, n0 = bx * 128;

    const int t = threadIdx.x, lane = t & 63, w = t >> 6;
    const int g = lane >> 4, c = lane & 15;
    const int wr = w >> 1, wcn = w & 1;            // 4 x 2 wave grid
    const int srow = t >> 3;                       // 0..63
    const int csw = (((t & 7) ^ (srow & 7)) * 8);  // pre-swizzled source chunk

    f32x4 acc[4][4] = {};

    for (int k0 = 0; k0 < 768; k0 += 64) {
        #pragma unroll
        for (int i = 0; i < 4; ++i) {              // A: 256 rows in 4 passes
            int row = i * 64 + srow;
            int ra = m0 + row; ra = ra < M ? ra : M - 1;
            __builtin_amdgcn_global_load_lds(
                (const AS1 unsigned int*)&A[(size_t)ra * 768 + k0 + csw],
                (AS3 unsigned int*)&As[i * 4096 + w * 512], 16, 0, 0);
        }
        #pragma unroll
        for (int i = 0; i < 2; ++i) {              // B: 128 rows in 2 passes
            int row = i * 64 + srow;
            __builtin_amdgcn_global_load_lds(
                (const AS1 unsigned int*)&Bt[(size_t)(n0 + row) * 768 + k0 + csw],
                (AS3 unsigned int*)&Bs[i * 4096 + w * 512], 16, 0, 0);
        }
        __syncthreads();
        #pragma unroll
        for (int kk = 0; kk < 2; ++kk) {
            short8 af[4], bfv[4];
            #pragma unroll
            for (int mf = 0; mf < 4; ++mf) {
                int rr = wr * 64 + mf * 16 + c;
                af[mf] = *(const short8*)&As[rr * 64 + (((kk * 4 + g) ^ (c & 7)) * 8)];
            }
            #pragma unroll
            for (int nf = 0; nf < 4; ++nf) {
                int rr = wcn * 64 + nf * 16 + c;
                bfv[nf] = *(const short8*)&Bs[rr * 64 + (((kk * 4 + g) ^ (c & 7)) * 8)];
            }
            __builtin_amdgcn_s_setprio(1);
            #pragma unroll
            for (int mf = 0; mf < 4; ++mf)
            #pragma unroll
            for (int nf = 0; nf < 4; ++nf)
                acc[mf][nf] = MFMA(af[mf], bfv[nf], acc[mf][nf]);
            __builtin_amdgcn_s_setprio(0);
        }
        __syncthreads();
    }

    #pragma unroll
    for (int mf = 0; mf < 4; ++mf)
    #pragma unroll
    for (int nf = 0; nf < 4; ++nf) {
        int n = n0 + wcn * 64 + nf * 16 + c;
        float bv = bias[n];
        int mb = m0 + wr * 64 + mf * 16 + g * 4;      // first of 4 consecutive m
        if (EPI == 1) {
            #pragma unroll
            for (int e = 0; e < 4; ++e) {
                int m = mb + e;
                if (m >= M) continue;
                f_out[(size_t)m * 768 + n] = acc[mf][nf][e] + bv;
            }
        } else {
            int which = n / 768;
            int rr = n - which * 768;
            int h = rr >> 6, d = rr & 63;
            if (which == 2) {
                int b0v = mb / 577, tok0 = mb - b0v * 577;
                if (mb + 3 < M && tok0 <= 573) {       // all 4 tokens in one batch
                    int bh = b0v * 12 + h;
                    uint2 pw;
                    pw.x = cvt_pk_bf16(acc[mf][nf][0] + bv, acc[mf][nf][1] + bv);
                    pw.y = cvt_pk_bf16(acc[mf][nf][2] + bv, acc[mf][nf][3] + bv);
                    *(uint2a2*)&vt_out[((size_t)bh * 64 + d) * VT_LD + tok0] = pw;
                } else {
                    #pragma unroll
                    for (int e = 0; e < 4; ++e) {
                        int m = mb + e;
                        if (m >= M) continue;
                        int b = m / 577, tok = m - b * 577;
                        vt_out[((size_t)(b * 12 + h) * 64 + d) * VT_LD + tok] =
                            f2bf(acc[mf][nf][e] + bv);
                    }
                }
            } else {
                #pragma unroll
                for (int e = 0; e < 4; ++e) {
                    int m = mb + e;
                    if (m >= M) continue;
                    int b = m / 577, tok = m - b * 577;
                    int bh = b * 12 + h;
                    if (which == 0)
                        q_out[((size_t)bh * 577 + tok) * 64 + d] = f2bf((acc[mf][nf][e] + bv) * QSCALE);
                    else
                        k_out[((size_t)bh * 577 + tok) * 64 + d] = f2bf(acc[mf][nf][e] + bv);
                }
            }
        }
    }
}

// ---------------- flash attention: LDS-staged K/V (2-phase dbuf), fixed-shift softmax --
__global__ __launch_bounds__(256, 3) void attn_flash(
    const unsigned short* __restrict__ Qg,
    const unsigned short* __restrict__ Kg,
    const unsigned short* __restrict__ Vtg,
    unsigned short* __restrict__ Og)
{
    __shared__ __align__(16) unsigned short KL[2][64][64];
    __shared__ __align__(16) unsigned short VL[2][64][64];
    __shared__ __align__(16) unsigned short pt[4][16][PT_LD];

    const int nwg = gridDim.x, orig = blockIdx.x;
    const int qd = nwg >> 3, jj8 = nwg & 7;
    const int xcd = orig & 7, jj = orig >> 3;
    const int wgid = (xcd < jj8 ? xcd * (qd + 1) : jj8 * (qd + 1) + (xcd - jj8) * qd) + jj;
    const int qt = wgid % 10;
    const int bh = wgid / 10;
    const int b = bh / 12, h = bh - b * 12;
    const int t = threadIdx.x, w = t >> 6, lane = t & 63;
    const int g = lane >> 4, c = lane & 15;
    const int rowi = t >> 3;                        // 0..31
    const int gch = ((t & 7) ^ (rowi & 7)) * 8;     // pre-swizzled source chunk

    const unsigned short* Qh = Qg + (size_t)bh * NTOK * 64;
    const unsigned short* Kh = Kg + (size_t)bh * NTOK * 64;
    const unsigned short* Vh = Vtg + (size_t)bh * 64 * VT_LD;

    const int q = qt * 64 + w * 16 + c;
    const int qc = q < NTOK ? q : NTOK - 1;

    short8 bq0 = *(const short8*)&Qh[(size_t)qc * 64 +      g * 8];
    short8 bq1 = *(const short8*)&Qh[(size_t)qc * 64 + 32 + g * 8];

    auto stage = [&](int buf, int kbase) {
        #pragma unroll
        for (int i = 0; i < 2; ++i) {
            __builtin_amdgcn_global_load_lds(
                (const AS1 unsigned int*)&Kh[(size_t)(kbase + i * 32 + rowi) * 64 + gch],
                (AS3 unsigned int*)(&KL[buf][0][0] + (i * 256 + w * 64) * 8), 16, 0, 0);
            __builtin_amdgcn_global_load_lds(
                (const AS1 unsigned int*)&Vh[(size_t)(i * 32 + rowi) * VT_LD + kbase + gch],
                (AS3 unsigned int*)(&VL[buf][0][0] + (i * 256 + w * 64) * 8), 16, 0, 0);
        }
    };

    f32x4 lsumv = {};
    f32x4 ot[4] = {};

    stage(0, 0);
    __syncthreads();

    int cur = 0;
    for (int kt = 0; kt < 9; ++kt) {
        if (kt < 8) stage(cur ^ 1, (kt + 1) * 64);
        short8 kf0[4], kf1[4];
        #pragma unroll
        for (int f = 0; f < 4; ++f) {
            const unsigned short* kr = &KL[cur][f * 16 + c][0];
            kf0[f] = *(const short8*)&kr[((g    ) ^ (c & 7)) * 8];
            kf1[f] = *(const short8*)&kr[((4 + g) ^ (c & 7)) * 8];
        }
        f32x4 st[4];
        __builtin_amdgcn_s_setprio(1);
        #pragma unroll
        for (int f = 0; f < 4; ++f) {
            f32x4 z = {};
            z = MFMA(kf0[f], bq0, z);
            z = MFMA(kf1[f], bq1, z);
            st[f] = z;
        }
        __builtin_amdgcn_s_setprio(0);
        #pragma unroll
        for (int f = 0; f < 4; ++f) {
            float p0 = exp2f(fminf(st[f][0], 60.f));
            float p1 = exp2f(fminf(st[f][1], 60.f));
            float p2 = exp2f(fminf(st[f][2], 60.f));
            float p3 = exp2f(fminf(st[f][3], 60.f));
            lsumv[0] += p0; lsumv[1] += p1; lsumv[2] += p2; lsumv[3] += p3;
            uint2 pw;
            pw.x = cvt_pk_bf16(p0, p1);
            pw.y = cvt_pk_bf16(p2, p3);
            *(uint2*)&pt[w][c][f * 16 + g * 4] = pw;
        }
        __builtin_amdgcn_s_setprio(1);
        #pragma unroll
        for (int kk = 0; kk < 2; ++kk) {
            short8 bp = *(const short8*)&pt[w][c][kk * 32 + g * 8];
            #pragma unroll
            for (int df = 0; df < 4; ++df) {
                const unsigned short* vr = &VL[cur][df * 16 + c][0];
                short8 av = *(const short8*)&vr[((kk * 4 + g) ^ (c & 7)) * 8];
                ot[df] = MFMA(av, bp, ot[df]);
            }
        }
        __builtin_amdgcn_s_setprio(0);
        __syncthreads();
        cur ^= 1;
    }

    float lsum = (lsumv[0] + lsumv[1]) + (lsumv[2] + lsumv[3]);
    lsum += __shfl_xor(lsum, 16);
    lsum += __shfl_xor(lsum, 32);

    // tail: key 576 (scalar)
    {
        const unsigned short* kp = &Kh[(size_t)576 * 64];
        float dot = 0.f;
        #pragma unroll
        for (int jx = 0; jx < 8; ++jx) {
            dot += bf2f((unsigned short)bq0[jx]) * bf2f(kp[g * 8 + jx]);
            dot += bf2f((unsigned short)bq1[jx]) * bf2f(kp[32 + g * 8 + jx]);
        }
        dot += __shfl_xor(dot, 16);
        dot += __shfl_xor(dot, 32);
        float p = exp2f(fminf(dot, 60.f));
        lsum += p;
        #pragma unroll
        for (int df = 0; df < 4; ++df)
        #pragma unroll
        for (int e = 0; e < 4; ++e)
            ot[df][e] += p * bf2f(Vh[(size_t)(df * 16 + g * 4 + e) * VT_LD + 576]);
    }

    float inv = 1.0f / lsum;
    if (q < NTOK) {
        size_t orow = ((size_t)b * NTOK + q) * 768 + h * 64;
        #pragma unroll
        for (int df = 0; df < 4; ++df) {
            uint2 ov;
            ov.x = cvt_pk_bf16(ot[df][0] * inv, ot[df][1] * inv);
            ov.y = cvt_pk_bf16(ot[df][2] * inv, ot[df][3] * inv);
            *(uint2*)&Og[orow + df * 16 + g * 4] = ov;
        }
    }
}

// ---------------- launch ----------------
extern "C" void kernel_launch(void* const* d_in, const int* in_sizes, int n_in,
                              void* d_out, int out_size, void* d_ws, size_t ws_size,
                              hipStream_t stream) {
    const float* x      = (const float*)d_in[0];
    const float* W_qkv  = (const float*)d_in[1];
    const float* b_qkv  = (const float*)d_in[2];
    const float* W_proj = (const float*)d_in[3];
    const float* b_proj = (const float*)d_in[4];
    float* out = (float*)d_out;

    const int B = 32, N = 577, C = 768, H = 12;
    const int M = B * N;            // 18464

    char* ws = (char*)d_ws;
    size_t off = 0;
    auto alloc = [&](size_t bytes) {
        char* p = ws + off;
        off += (bytes + 255) & ~(size_t)255;
        return p;
    };
    unsigned short* xb    = (unsigned short*)alloc((size_t)M * C * 2);
    unsigned short* wqkvt = (unsigned short*)alloc((size_t)3 * C * C * 2);
    unsigned short* wprjt = (unsigned short*)alloc((size_t)C * C * 2);
    unsigned short* Qb    = (unsigned short*)alloc((size_t)B * H * N * 64 * 2);
    unsigned short* Kb    = (unsigned short*)alloc((size_t)B * H * N * 64 * 2);
    unsigned short* Vtb   = (unsigned short*)alloc((size_t)B * H * 64 * VT_LD * 2);
    unsigned short* attn  = xb;     // x_bf16 dead after QKV GEMM

    // fused prep: cvt (13848) + W_qkv^T (1728) + W_proj^T (576) = 16152 blocks
    prep<<<dim3(16152), 256, 0, stream>>>(x, xb, W_qkv, wqkvt, W_proj, wprjt);

    // QKV: 256x128 tiles, 73 x 18 = 1314 blocks (R13-proven)
    gemm256x128<0><<<dim3(73 * 18), 512, 0, stream>>>(
        xb, wqkvt, b_qkv, Qb, Kb, Vtb, nullptr, M, 18);

    attn_flash<<<dim3(3840), 256, 0, stream>>>(Qb, Kb, Vtb, attn);

    // proj: 256x128 tiles, 73 x 6 = 438 blocks
    gemm256x128<1><<<dim3(73 * 6), 512, 0, stream>>>(
        attn, wprjt, b_proj, nullptr, nullptr, nullptr, out, M, 6);
}